// Round 15
// baseline (125.565 us; speedup 1.0000x reference)
//
#include <hip/hip_runtime.h>
#include <hip/hip_cooperative_groups.h>

namespace cg = cooperative_groups;

#define DD 32
#define PP 32
#define HH 64
#define TPB 512
#define ROWS 512

// main LUT: 32 x 128 scalars over [M_LO, M_HI] (lives in LDS during main phase)
#define M_NE 128
#define M_LO (-8.0f)
#define M_HI (8.0f)
// inter LUT: 32 x 96 x 96 bf16x4 cells over [I_LO, I_HI]^2
#define I_NE 96
#define I_LO (-6.5f)
#define I_HI (6.5f)
#define I_CELLS (I_NE * I_NE)                      // 9216

// builder virtual blocks (TPB=512)
#define VB_MAIN ((DD * M_NE) / TPB)                // 8
#define VB_PER_P (I_CELLS / TPB)                   // 18
#define VB_TOTAL (VB_MAIN + PP * VB_PER_P)         // 584

// s_t row stride: 36 floats = 144 B (16B-aligned for b128)
#define TSTR 36
// s_x row stride: 33 floats (odd -> conflict-free scalar access)
#define XSTR 33

__device__ __forceinline__ float silu_fast(float t) {
    const float LOG2E = 1.4426950408889634f;
    return t * __builtin_amdgcn_rcpf(1.f + __builtin_amdgcn_exp2f(-t * LOG2E));
}

__device__ __forceinline__ unsigned short f2bf(float f) {
    unsigned u = __float_as_uint(f);
    u += 0x7FFF + ((u >> 16) & 1);          // round-to-nearest-even
    return (unsigned short)(u >> 16);
}

__device__ __forceinline__ float bf2f(unsigned short s) {
    return __uint_as_float((unsigned)s << 16);
}

// one p-column bilerp; writes ZVAR and accumulates dot
#define IEVAL(PIDX, ZVAR) do {                                               \
    const int p_  = (PIDX);                                                  \
    const int i0_ = s_p0[p_], i1_ = s_p1[p_];                                \
    float u_  = fmaf(s_x[r][i0_], I_INVH, s_io0[p_]);                        \
    float w_  = fmaf(s_x[r][i1_], I_INVH, s_io1[p_]);                        \
    int iu_ = (int)floorf(u_);                                               \
    int iv_ = (int)floorf(w_);                                               \
    iu_ = iu_ < 0 ? 0 : (iu_ > I_NE - 2 ? I_NE - 2 : iu_);                   \
    iv_ = iv_ < 0 ? 0 : (iv_ > I_NE - 2 ? I_NE - 2 : iv_);                   \
    float fu_ = u_ - (float)iu_;                                             \
    float fv_ = w_ - (float)iv_;                                             \
    ushort4 cell_ = LUTi4[(size_t)p_ * I_CELLS + iu_ * I_NE + iv_];          \
    float a00_ = bf2f(cell_.x), a01_ = bf2f(cell_.y);                        \
    float a10_ = bf2f(cell_.z), a11_ = bf2f(cell_.w);                        \
    float r0_ = fmaf(fv_, a01_ - a00_, a00_);                                \
    float r1_ = fmaf(fv_, a11_ - a10_, a10_);                                \
    ZVAR = fmaf(fu_, r1_ - r0_, r0_);                                        \
    dot = fmaf(ZVAR, s_wf[DD + p_], dot);                                    \
} while (0)

// ---------------- fused cooperative kernel: build LUTs + grid sync + main ----
__global__ __launch_bounds__(TPB, 2) void qgam_fused(
    const float* __restrict__ X,
    const float* __restrict__ lwm,
    const float* __restrict__ bias_main,
    const float* __restrict__ vm,
    const float* __restrict__ lwi,
    const float* __restrict__ bias_inter,
    const float* __restrict__ vi,
    const float* __restrict__ W_final,
    const float* __restrict__ b_final,
    const int* __restrict__ pairs,
    float* __restrict__ LUTm,
    unsigned short* __restrict__ LUTi,
    float* __restrict__ out,
    float* __restrict__ Zout,
    int nrows)
{
    const float LOG2E  = 1.4426950408889634f;
    const float M_INVH = (float)(M_NE - 1) / (M_HI - M_LO);
    const float I_INVH = (float)(I_NE - 1) / (I_HI - I_LO);

    __shared__ float s_lutm[DD * M_NE];    // 16 KB
    __shared__ float s_x[ROWS][XSTR];      // 66 KB
    __shared__ float s_t[ROWS][TSTR];      // 72 KB (phase A: aliased as sew/sv)
    __shared__ float s_wf[DD + PP];
    __shared__ float s_moff[DD];
    __shared__ float s_io0[PP], s_io1[PP];
    __shared__ int   s_p0[PP], s_p1[PP];

    const int tid = threadIdx.x;

    // ================= Phase A: build LUTm + LUTi ==========================
    {
        float2* sew = reinterpret_cast<float2*>(&s_t[0][0]);   // 64 float2
        float*  sv  = reinterpret_cast<float*>(&s_t[0][0]) + 128;

        for (int vb = blockIdx.x; vb < VB_TOTAL; vb += gridDim.x) {
            if (vb < VB_MAIN) {
                const float h = (M_HI - M_LO) / (float)(M_NE - 1);
                int idx = vb * TPB + tid;
                int d = idx >> 7;
                int i = idx & (M_NE - 1);
                float s = M_LO + (float)i * h;
                float acc = 0.f;
                #pragma unroll 8
                for (int k = 0; k < HH; ++k) {
                    float w = __builtin_amdgcn_exp2f(lwm[d * HH + k] * LOG2E);
                    acc = fmaf(silu_fast(s * w), vm[d * HH + k], acc);
                }
                LUTm[idx] = acc;
            } else {
                const float h = (I_HI - I_LO) / (float)(I_NE - 1);
                const int rel = vb - VB_MAIN;
                const int p   = rel / VB_PER_P;          // uniform per vb
                const int cip = (rel % VB_PER_P) * TPB + tid;   // 0..9215
                const int i   = cip / I_NE;
                const int j   = cip - i * I_NE;
                if (tid < HH) {
                    sew[tid] = make_float2(
                        __builtin_amdgcn_exp2f(lwi[(p * HH + tid) * 2 + 0] * LOG2E),
                        __builtin_amdgcn_exp2f(lwi[(p * HH + tid) * 2 + 1] * LOG2E));
                    sv[tid] = vi[p * HH + tid];
                }
                __syncthreads();
                float c0 = I_LO + (float)i * h;
                float c1 = I_LO + (float)j * h;
                float acc = 0.f;
                #pragma unroll 8
                for (int k = 0; k < HH; ++k) {
                    float a = fmaf(c0, sew[k].x, c1 * sew[k].y);
                    acc = fmaf(silu_fast(a), sv[k], acc);
                }
                unsigned short ab = f2bf(acc);
                unsigned short* cb = LUTi + (size_t)p * I_CELLS * 4;
                if (i < I_NE - 1 && j < I_NE - 1) cb[((i    ) * I_NE + j    ) * 4 + 0] = ab;
                if (i < I_NE - 1 && j > 0)        cb[((i    ) * I_NE + j - 1) * 4 + 1] = ab;
                if (i > 0        && j < I_NE - 1) cb[((i - 1) * I_NE + j    ) * 4 + 2] = ab;
                if (i > 0        && j > 0)        cb[((i - 1) * I_NE + j - 1) * 4 + 3] = ab;
                __syncthreads();
            }
        }
    }

    __threadfence();                       // device-scope release of LUT writes
    cg::this_grid().sync();                // all LUTs complete

    // ================= Phase B: main computation ===========================
    // copy main LUT -> LDS
    {
        const float4* __restrict__ lm4 = reinterpret_cast<const float4*>(LUTm);
        float4* __restrict__ sl4 = reinterpret_cast<float4*>(s_lutm);
        #pragma unroll
        for (int k = 0; k < 2; ++k)
            sl4[k * TPB + tid] = lm4[k * TPB + tid];
    }
    if (tid < DD + PP) s_wf[tid] = W_final[tid];
    if (tid < PP) {
        s_moff[tid] = -(bias_main[tid] + M_LO) * M_INVH;
        s_io0[tid]  = -(bias_inter[2 * tid + 0] + I_LO) * I_INVH;
        s_io1[tid]  = -(bias_inter[2 * tid + 1] + I_LO) * I_INVH;
        s_p0[tid]   = pairs[2 * tid + 0];
        s_p1[tid]   = pairs[2 * tid + 1];
    }
    const ushort4* __restrict__ LUTi4 = reinterpret_cast<const ushort4*>(LUTi);

    for (int base = blockIdx.x * ROWS; base < nrows; base += gridDim.x * ROWS) {
        __syncthreads();                   // s_x/s_t safe to overwrite

        // stage X tile coalesced -> LDS row-major
        {
            const float4* __restrict__ Xv =
                reinterpret_cast<const float4*>(X) + (size_t)base * (DD / 4);
            #pragma unroll
            for (int k = 0; k < 8; ++k) {
                const int fi = k * TPB + tid;       // 0..4095 float4 units
                const int rl = fi >> 3;
                const int c  = (fi & 7) * 4;
                if (base + rl < nrows) {
                    float4 v = Xv[fi];
                    s_x[rl][c + 0] = v.x;
                    s_x[rl][c + 1] = v.y;
                    s_x[rl][c + 2] = v.z;
                    s_x[rl][c + 3] = v.w;
                }
            }
        }
        __syncthreads();

        const int r = tid;
        const int n = base + r;
        float dot = b_final[0];

        // main part: 32 LDS lerps, buffered x4 -> b128 s_t writes
        #pragma unroll
        for (int d4 = 0; d4 < DD / 4; ++d4) {
            float z[4];
            #pragma unroll
            for (int j = 0; j < 4; ++j) {
                const int d = d4 * 4 + j;
                float u  = fmaf(s_x[r][d], M_INVH, s_moff[d]);
                int   ii = (int)floorf(u);
                ii = ii < 0 ? 0 : (ii > M_NE - 2 ? M_NE - 2 : ii);
                float f  = u - (float)ii;
                float t0 = s_lutm[(d << 7) + ii];
                float t1 = s_lutm[(d << 7) + ii + 1];
                z[j] = fmaf(f, t1 - t0, t0);
                dot = fmaf(z[j], s_wf[d], dot);
            }
            *reinterpret_cast<float4*>(&s_t[r][d4 * 4]) =
                make_float4(z[0], z[1], z[2], z[3]);
        }

        // flush round 0: Z cols 0..31
        __syncthreads();
        #pragma unroll
        for (int i = 0; i < 8; ++i) {
            const int fi   = i * TPB + tid;
            const int rowl = fi >> 3;
            const int c4   = (fi & 7) * 4;
            const int row  = base + rowl;
            if (row < nrows) {
                float4 v = *reinterpret_cast<const float4*>(&s_t[rowl][c4]);
                *reinterpret_cast<float4*>(&Zout[(size_t)row * (DD + PP) + c4]) = v;
            }
        }
        __syncthreads();

        // inter part: per-p barrier lockstep
        #pragma unroll 1
        for (int p4 = 0; p4 < PP / 4; ++p4) {
            const int pb = p4 * 4;
            float z0, z1, z2, z3;
            IEVAL(pb + 0, z0); __syncthreads();
            IEVAL(pb + 1, z1); __syncthreads();
            IEVAL(pb + 2, z2); __syncthreads();
            IEVAL(pb + 3, z3); __syncthreads();
            *reinterpret_cast<float4*>(&s_t[r][pb]) = make_float4(z0, z1, z2, z3);
        }

        if (n < nrows) out[n] = dot;

        // flush round 1: Z cols 32..63
        __syncthreads();
        #pragma unroll
        for (int i = 0; i < 8; ++i) {
            const int fi   = i * TPB + tid;
            const int rowl = fi >> 3;
            const int c4   = (fi & 7) * 4;
            const int row  = base + rowl;
            if (row < nrows) {
                float4 v = *reinterpret_cast<const float4*>(&s_t[rowl][c4]);
                *reinterpret_cast<float4*>(&Zout[(size_t)row * (DD + PP) + DD + c4]) = v;
            }
        }
    }
}

extern "C" void kernel_launch(void* const* d_in, const int* in_sizes, int n_in,
                              void* d_out, int out_size, void* d_ws, size_t ws_size,
                              hipStream_t stream) {
    const float* X   = (const float*)d_in[0];
    const float* lwm = (const float*)d_in[1];
    const float* bm  = (const float*)d_in[2];
    const float* vm  = (const float*)d_in[3];
    const float* lwi = (const float*)d_in[4];
    const float* bi  = (const float*)d_in[5];
    const float* vi  = (const float*)d_in[6];
    const float* wf  = (const float*)d_in[7];
    const float* bf  = (const float*)d_in[8];
    const int* pairs = (const int*)d_in[9];

    int nrows = in_sizes[0] / DD;
    float* out = (float*)d_out;          // (N,)
    float* Z   = out + nrows;            // (N, 64)

    float*          LUTm = (float*)d_ws;                 // 32*128*4B = 16 KB
    unsigned short* LUTi = (unsigned short*)((char*)d_ws +
                           ((DD * M_NE * sizeof(float) + 255) & ~255));
                           // 32*9216 cells * 8B = 2.36 MB

    int ntiles = (nrows + ROWS - 1) / ROWS;
    int grid   = ntiles < 256 ? ntiles : 256;

    void* args[] = {
        (void*)&X, (void*)&lwm, (void*)&bm, (void*)&vm, (void*)&lwi,
        (void*)&bi, (void*)&vi, (void*)&wf, (void*)&bf, (void*)&pairs,
        (void*)&LUTm, (void*)&LUTi, (void*)&out, (void*)&Z, (void*)&nrows
    };
    hipLaunchCooperativeKernel((const void*)qgam_fused, dim3(grid), dim3(TPB),
                               args, 0, stream);
}

// Round 16
// 32.571 us; speedup vs baseline: 3.8551x; 3.8551x over previous
//
#include <hip/hip_runtime.h>

#define DD 32
#define PP 32
#define HH 64
#define TPB 512
#define ROWS 512

// main LUT: 32 x 128 scalars over [M_LO, M_HI] (lives in LDS during main kernel)
#define M_NE 128
#define M_LO (-8.0f)
#define M_HI (8.0f)
// inter LUT: 32 x 96 x 96 bf16x4 cells over [I_LO, I_HI]^2
#define I_NE 96
#define I_LO (-6.5f)
#define I_HI (6.5f)
#define I_CELLS (I_NE * I_NE)                      // 9216

#define BTPB 256
#define MAIN_BLOCKS ((DD * M_NE) / BTPB)           // 16
#define BLOCKS_PER_P (I_CELLS / BTPB)              // 36
#define INTER_BLOCKS (PP * BLOCKS_PER_P)           // 1152

// s_t row stride: 36 floats = 144 B (16B-aligned for b128, bank-quad +4/row)
#define TSTR 36
// s_x row stride: 33 floats (odd -> conflict-free scalar access)
#define XSTR 33

__device__ __forceinline__ float silu_fast(float t) {
    const float LOG2E = 1.4426950408889634f;
    return t * __builtin_amdgcn_rcpf(1.f + __builtin_amdgcn_exp2f(-t * LOG2E));
}

__device__ __forceinline__ unsigned short f2bf(float f) {
    unsigned u = __float_as_uint(f);
    u += 0x7FFF + ((u >> 16) & 1);          // round-to-nearest-even
    return (unsigned short)(u >> 16);
}

__device__ __forceinline__ float bf2f(unsigned short s) {
    return __uint_as_float((unsigned)s << 16);
}

// ---------------- fused LUT builder ----------------
__global__ void build_luts(const float* __restrict__ lwm,
                           const float* __restrict__ vm,
                           const float* __restrict__ lwi,
                           const float* __restrict__ vi,
                           float* __restrict__ LUTm,
                           unsigned short* __restrict__ LUTi)   // [32][96][96][4] bf16
{
    const float LOG2E = 1.4426950408889634f;
    __shared__ float2 sew[HH];
    __shared__ float  sv[HH];

    if (blockIdx.x < MAIN_BLOCKS) {
        const float h = (M_HI - M_LO) / (float)(M_NE - 1);
        int idx = blockIdx.x * BTPB + threadIdx.x;
        int d = idx >> 7;                 // 2 d's per block
        int i = idx & (M_NE - 1);
        float s = M_LO + (float)i * h;
        float acc = 0.f;
        #pragma unroll 8
        for (int k = 0; k < HH; ++k) {
            float w = __builtin_amdgcn_exp2f(lwm[d * HH + k] * LOG2E);
            acc = fmaf(silu_fast(s * w), vm[d * HH + k], acc);
        }
        LUTm[idx] = acc;
    } else {
        const float h = (I_HI - I_LO) / (float)(I_NE - 1);
        const int rel = blockIdx.x - MAIN_BLOCKS;
        const int p   = rel / BLOCKS_PER_P;        // uniform per block
        const int cip = (rel % BLOCKS_PER_P) * BTPB + threadIdx.x;  // 0..9215
        const int i   = cip / I_NE;
        const int j   = cip - i * I_NE;
        if (threadIdx.x < HH) {
            int t = threadIdx.x;
            sew[t] = make_float2(
                __builtin_amdgcn_exp2f(lwi[(p * HH + t) * 2 + 0] * LOG2E),
                __builtin_amdgcn_exp2f(lwi[(p * HH + t) * 2 + 1] * LOG2E));
            sv[t] = vi[p * HH + t];
        }
        __syncthreads();
        float c0 = I_LO + (float)i * h;
        float c1 = I_LO + (float)j * h;
        float acc = 0.f;
        #pragma unroll 8
        for (int k = 0; k < HH; ++k) {
            float a = fmaf(c0, sew[k].x, c1 * sew[k].y);
            acc = fmaf(silu_fast(a), sv[k], acc);
        }
        unsigned short ab = f2bf(acc);
        unsigned short* cb = LUTi + (size_t)p * I_CELLS * 4;
        // scatter corner value into the <=4 cells that reference it
        if (i < I_NE - 1 && j < I_NE - 1) cb[((i    ) * I_NE + j    ) * 4 + 0] = ab;
        if (i < I_NE - 1 && j > 0)        cb[((i    ) * I_NE + j - 1) * 4 + 1] = ab;
        if (i > 0        && j < I_NE - 1) cb[((i - 1) * I_NE + j    ) * 4 + 2] = ab;
        if (i > 0        && j > 0)        cb[((i - 1) * I_NE + j - 1) * 4 + 3] = ab;
    }
}

// one p-column bilerp; writes ZVAR and accumulates dot
#define IEVAL(PIDX, ZVAR) do {                                               \
    const int p_  = (PIDX);                                                  \
    const int i0_ = s_p0[p_], i1_ = s_p1[p_];                                \
    float u_  = fmaf(s_x[r][i0_], I_INVH, s_io0[p_]);                        \
    float w_  = fmaf(s_x[r][i1_], I_INVH, s_io1[p_]);                        \
    int iu_ = (int)floorf(u_);                                               \
    int iv_ = (int)floorf(w_);                                               \
    iu_ = iu_ < 0 ? 0 : (iu_ > I_NE - 2 ? I_NE - 2 : iu_);                   \
    iv_ = iv_ < 0 ? 0 : (iv_ > I_NE - 2 ? I_NE - 2 : iv_);                   \
    float fu_ = u_ - (float)iu_;                                             \
    float fv_ = w_ - (float)iv_;                                             \
    ushort4 cell_ = LUTi[(size_t)p_ * I_CELLS + iu_ * I_NE + iv_];           \
    float a00_ = bf2f(cell_.x), a01_ = bf2f(cell_.y);                        \
    float a10_ = bf2f(cell_.z), a11_ = bf2f(cell_.w);                        \
    float r0_ = fmaf(fv_, a01_ - a00_, a00_);                                \
    float r1_ = fmaf(fv_, a11_ - a10_, a10_);                                \
    ZVAR = fmaf(fu_, r1_ - r0_, r0_);                                        \
    dot = fmaf(ZVAR, s_wf[DD + p_], dot);                                    \
} while (0)

// ---------------- main kernel: per-p barrier lockstep (L1-resident region) ----
__global__ __launch_bounds__(TPB, 2) void qgam_main(
    const float* __restrict__ X,
    const float* __restrict__ bias_main,
    const float* __restrict__ bias_inter,
    const float* __restrict__ W_final,
    const float* __restrict__ b_final,
    const int* __restrict__ pairs,
    const float* __restrict__ LUTm,
    const ushort4* __restrict__ LUTi,
    float* __restrict__ out,
    float* __restrict__ Zout,
    int nrows)
{
    const float M_INVH = (float)(M_NE - 1) / (M_HI - M_LO);
    const float I_INVH = (float)(I_NE - 1) / (I_HI - I_LO);

    __shared__ float s_lutm[DD * M_NE];    // 16 KB
    __shared__ float s_x[ROWS][XSTR];      // 66 KB  row-major
    __shared__ float s_t[ROWS][TSTR];      // 72 KB  row-major, b128 access
    __shared__ float s_wf[DD + PP];
    __shared__ float s_moff[DD];           // -(bm[d]+M_LO)*M_INVH
    __shared__ float s_io0[PP], s_io1[PP];
    __shared__ int   s_p0[PP], s_p1[PP];

    const int tid  = threadIdx.x;
    const int base = blockIdx.x * ROWS;

    // copy main LUT -> LDS (coalesced, L2-resident)
    {
        const float4* __restrict__ lm4 = reinterpret_cast<const float4*>(LUTm);
        float4* __restrict__ sl4 = reinterpret_cast<float4*>(s_lutm);
        #pragma unroll
        for (int k = 0; k < 2; ++k)
            sl4[k * TPB + tid] = lm4[k * TPB + tid];
    }
    // stage X tile coalesced -> LDS row-major (512 rows x 32 cols)
    {
        const float4* __restrict__ Xv =
            reinterpret_cast<const float4*>(X) + (size_t)base * (DD / 4);
        #pragma unroll
        for (int k = 0; k < 8; ++k) {
            const int fi = k * TPB + tid;           // 0..4095 float4 units
            const int rl = fi >> 3;
            const int c  = (fi & 7) * 4;
            if (base + rl < nrows) {
                float4 v = Xv[fi];
                s_x[rl][c + 0] = v.x;
                s_x[rl][c + 1] = v.y;
                s_x[rl][c + 2] = v.z;
                s_x[rl][c + 3] = v.w;
            }
        }
    }
    if (tid < DD + PP) s_wf[tid] = W_final[tid];
    if (tid < PP) {
        s_moff[tid] = -(bias_main[tid] + M_LO) * M_INVH;
        s_io0[tid]  = -(bias_inter[2 * tid + 0] + I_LO) * I_INVH;
        s_io1[tid]  = -(bias_inter[2 * tid + 1] + I_LO) * I_INVH;
        s_p0[tid]   = pairs[2 * tid + 0];
        s_p1[tid]   = pairs[2 * tid + 1];
    }
    __syncthreads();

    const int r = tid;                    // this thread's local row
    const int n = base + r;

    float dot = b_final[0];

    // ---- main part: 32 LDS lerps, buffered x4 -> b128 s_t writes ----
    #pragma unroll
    for (int d4 = 0; d4 < DD / 4; ++d4) {
        float z[4];
        #pragma unroll
        for (int j = 0; j < 4; ++j) {
            const int d = d4 * 4 + j;
            float u  = fmaf(s_x[r][d], M_INVH, s_moff[d]);
            int   ii = (int)floorf(u);
            ii = ii < 0 ? 0 : (ii > M_NE - 2 ? M_NE - 2 : ii);
            float f  = u - (float)ii;
            float t0 = s_lutm[(d << 7) + ii];
            float t1 = s_lutm[(d << 7) + ii + 1];
            z[j] = fmaf(f, t1 - t0, t0);
            dot = fmaf(z[j], s_wf[d], dot);
        }
        *reinterpret_cast<float4*>(&s_t[r][d4 * 4]) =
            make_float4(z[0], z[1], z[2], z[3]);
    }

    // flush round 0: Z cols 0..31 (b128 LDS reads, full-line coalesced stores)
    __syncthreads();
    #pragma unroll
    for (int i = 0; i < 8; ++i) {
        const int fi   = i * TPB + tid;   // 0..4095
        const int rowl = fi >> 3;
        const int c4   = (fi & 7) * 4;
        const int row  = base + rowl;
        if (row < nrows) {
            float4 v = *reinterpret_cast<const float4*>(&s_t[rowl][c4]);
            *reinterpret_cast<float4*>(&Zout[(size_t)row * (DD + PP) + c4]) = v;
        }
    }
    __syncthreads();

    // ---- inter part: per-p barrier keeps all 8 waves on ONE hot region ----
    #pragma unroll 1
    for (int p4 = 0; p4 < PP / 4; ++p4) {
        const int pb = p4 * 4;
        float z0, z1, z2, z3;
        IEVAL(pb + 0, z0); __syncthreads();
        IEVAL(pb + 1, z1); __syncthreads();
        IEVAL(pb + 2, z2); __syncthreads();
        IEVAL(pb + 3, z3); __syncthreads();
        *reinterpret_cast<float4*>(&s_t[r][pb]) = make_float4(z0, z1, z2, z3);
    }

    if (n < nrows) out[n] = dot;

    // flush round 1: Z cols 32..63
    __syncthreads();
    #pragma unroll
    for (int i = 0; i < 8; ++i) {
        const int fi   = i * TPB + tid;
        const int rowl = fi >> 3;
        const int c4   = (fi & 7) * 4;
        const int row  = base + rowl;
        if (row < nrows) {
            float4 v = *reinterpret_cast<const float4*>(&s_t[rowl][c4]);
            *reinterpret_cast<float4*>(&Zout[(size_t)row * (DD + PP) + DD + c4]) = v;
        }
    }
}

extern "C" void kernel_launch(void* const* d_in, const int* in_sizes, int n_in,
                              void* d_out, int out_size, void* d_ws, size_t ws_size,
                              hipStream_t stream) {
    const float* X   = (const float*)d_in[0];
    const float* lwm = (const float*)d_in[1];
    const float* bm  = (const float*)d_in[2];
    const float* vm  = (const float*)d_in[3];
    const float* lwi = (const float*)d_in[4];
    const float* bi  = (const float*)d_in[5];
    const float* vi  = (const float*)d_in[6];
    const float* wf  = (const float*)d_in[7];
    const float* bf  = (const float*)d_in[8];
    const int* pairs = (const int*)d_in[9];

    const int nrows = in_sizes[0] / DD;
    float* out = (float*)d_out;          // (N,)
    float* Z   = out + nrows;            // (N, 64)

    float*          LUTm = (float*)d_ws;                 // 32*128*4B = 16 KB
    unsigned short* LUTi = (unsigned short*)((char*)d_ws +
                           ((DD * M_NE * sizeof(float) + 255) & ~255));
                           // 32*9216 cells * 8B = 2.36 MB

    build_luts<<<MAIN_BLOCKS + INTER_BLOCKS, BTPB, 0, stream>>>(lwm, vm, lwi, vi,
                                                                LUTm, LUTi);

    const int grid = (nrows + ROWS - 1) / ROWS;
    qgam_main<<<grid, TPB, 0, stream>>>(X, bm, bi, wf, bf, pairs, LUTm,
                                        (const ushort4*)LUTi, out, Z, nrows);
}